// Round 3
// baseline (312.578 us; speedup 1.0000x reference)
//
#include <hip/hip_runtime.h>
#include <math.h>

#define B 16
#define C 2
#define T 2000
#define F 257
#define NC 100           // chunks per (b,f)
#define L  (T / NC)      // 20 timesteps per chunk
#define NPAIR ((F + 1) / 2)   // 129 f-pairs per (b,c); last pair is f=256 solo

#define RES_SIZE   (B * C * T * F * 2)   // 32,896,000
#define OFF_SFINAL (RES_SIZE)            // + B*F
#define OFF_SMOOTH (RES_SIZE + B * F)    // + B*T*F

#define N_CAR2  (B * NC * NPAIR)           // 206,400 f-pair threads (carries / phase-2)
#define G0      ((N_CAR2 + 255) / 256)     // 807 blocks
#define SLAB4   (T * F * 2 / 4)            // 257,000 float4 per (b, ch1) slab
#define N_V4    (B * SLAB4)                // 4,112,000 float4 threads for ch1
#define G1      ((N_V4 + 255) / 256)       // 16,063 blocks

__device__ __forceinline__ float sigmoidf_(float x) {
    return 1.0f / (1.0f + expf(-x));
}

// Phase 1 (fused): blocks [0,G1) do channel-1 elementwise (float4);
// blocks [G1, G1+G0) compute ch0 per-chunk carries, one f-PAIR per thread
// (two independent recurrence chains, 16 B/lane/step).
// Carries run LAST so ch0 input is as fresh as possible in L3 when
// phase 2 re-reads it.
__global__ __launch_bounds__(256) void k_phase1(const float* __restrict__ input,
                                                const float* __restrict__ alpha_param,
                                                const float* __restrict__ weights,
                                                const float* __restrict__ bias,
                                                float* __restrict__ carry,
                                                float* __restrict__ out) {
    int bid = blockIdx.x;
    if (bid < G1) {
        // ---- channel 1: pure elementwise, float4-vectorized ----
        int idx = bid * 256 + threadIdx.x;
        if (idx >= N_V4) return;
        int b   = idx / SLAB4;
        int rem = idx - b * SLAB4;

        const float4* ip = (const float4*)(input + ((size_t)(b * C + 1) * T) * F * 2) + rem;
        float4 v = *ip;

        int e  = rem * 2;              // float2 index within slab
        int f0 = e % F;                // magic-mul, F=257 constant
        int f1 = (f0 + 1 == F) ? 0 : (f0 + 1);

        float w0 = weights[F + f0], w1 = weights[F + f1];
        float q0 = bias[F + f0],    q1 = bias[F + f1];

        float inv0 = 1.0f / (sqrtf(v.x * v.x + v.y * v.y) + 1e-8f);
        float inv1 = 1.0f / (sqrtf(v.z * v.z + v.w * v.w) + 1e-8f);

        float4 rr;
        rr.x = v.x * inv0 * w0 + q0;
        rr.y = v.y * inv0 * w0 + q0;
        rr.z = v.z * inv1 * w1 + q1;
        rr.w = v.w * inv1 * w1 + q1;

        float4* rp = (float4*)(out + ((size_t)(b * C + 1) * T) * F * 2) + rem;
        *rp = rr;
    } else {
        // ---- chunk carries: recurrence with s=0 over L steps, f-pair/thread ----
        int tid = (bid - G1) * 256 + threadIdx.x;
        if (tid >= N_CAR2) return;
        int p = tid % NPAIR;
        int r = tid / NPAIR;
        int c = r % NC;
        int b = r / NC;
        int f0 = 2 * p;
        bool has2 = (f0 + 1 < F);
        int f1 = has2 ? f0 + 1 : f0;

        float a0 = sigmoidf_(alpha_param[f0]);
        float a1 = sigmoidf_(alpha_param[f1]);
        float be0 = 1.0f - a0, be1 = 1.0f - a1;

        const float2* base = (const float2*)input
                           + ((size_t)(b * C + 0) * T + (size_t)c * L) * F;
        float s0 = 0.0f, s1 = 0.0f;
#pragma unroll 5
        for (int t = 0; t < L; ++t) {
            float2 v0 = base[(size_t)t * F + f0];
            float2 v1 = base[(size_t)t * F + f1];
            s0 = be0 * s0 + a0 * (v0.x * v0.x + v0.y * v0.y);
            s1 = be1 * s1 + a1 * (v1.x * v1.x + v1.y * v1.y);
        }
        float* cw = carry + ((size_t)b * NC + c) * F;
        cw[f0] = s0;
        if (has2) cw[f1] = s1;
    }
}

// Phase 2 (fused scan + final): each (b,c,p) thread folds its own chunk-start
// states for its f-pair from the L2-resident carry buffer, runs the exact
// per-step recurrence for both columns (2 independent chains), writes
// res ch0 + smooth; c==NC-1 threads emit s_final.
__global__ __launch_bounds__(256) void k_phase2(const float* __restrict__ input,
                                                const float* __restrict__ s_1,
                                                const float* __restrict__ alpha_param,
                                                const float* __restrict__ weights,
                                                const float* __restrict__ bias,
                                                const float* __restrict__ carry,
                                                float* __restrict__ out) {
    int tid = blockIdx.x * 256 + threadIdx.x;
    if (tid >= N_CAR2) return;
    int p = tid % NPAIR;
    int r = tid / NPAIR;
    int c = r % NC;
    int b = r / NC;
    int f0 = 2 * p;
    bool has2 = (f0 + 1 < F);
    int f1 = has2 ? f0 + 1 : f0;

    float a0 = sigmoidf_(alpha_param[f0]);
    float a1 = sigmoidf_(alpha_param[f1]);
    float be0 = 1.0f - a0, be1 = 1.0f - a1;
    float bL0 = 1.0f, bL1 = 1.0f;
#pragma unroll
    for (int i = 0; i < L; ++i) { bL0 *= be0; bL1 *= be1; }
    float bL0_2 = bL0 * bL0, bL1_2 = bL1 * bL1;

    // redundant per-thread prefix over carries (L2-resident, 1.6 MB buffer);
    // two chains, 2-way unrolled each (4 independent loads per iteration)
    const float* cp = carry + (size_t)b * NC * F;
    float s0 = s_1[b * F + f0];
    float s1 = s_1[b * F + f1];
    int j = 0;
    for (; j + 2 <= c; j += 2) {
        float c00 = cp[(size_t)(j    ) * F + f0];
        float c01 = cp[(size_t)(j + 1) * F + f0];
        float c10 = cp[(size_t)(j    ) * F + f1];
        float c11 = cp[(size_t)(j + 1) * F + f1];
        s0 = fmaf(bL0_2, s0, fmaf(bL0, c00, c01));
        s1 = fmaf(bL1_2, s1, fmaf(bL1, c10, c11));
    }
    if (j < c) {
        s0 = fmaf(bL0, s0, cp[(size_t)j * F + f0]);
        s1 = fmaf(bL1, s1, cp[(size_t)j * F + f1]);
    }

    float w0 = weights[f0], q0 = bias[f0];   // channel 0
    float w1 = weights[f1], q1 = bias[f1];

    const float2* inb = (const float2*)input
                      + ((size_t)(b * C + 0) * T + (size_t)c * L) * F;
    float2* resb = (float2*)out
                 + ((size_t)(b * C + 0) * T + (size_t)c * L) * F;
    float* smb = out + OFF_SMOOTH + ((size_t)b * T + (size_t)c * L) * F;

#pragma unroll 5
    for (int t = 0; t < L; ++t) {
        float2 v0 = inb[(size_t)t * F + f0];
        float2 v1 = inb[(size_t)t * F + f1];
        s0 = be0 * s0 + a0 * (v0.x * v0.x + v0.y * v0.y);
        s1 = be1 * s1 + a1 * (v1.x * v1.x + v1.y * v1.y);
        float sm0 = sqrtf(s0), sm1 = sqrtf(s1);
        float inv0 = 1.0f / (sm0 + 1e-8f);
        float inv1 = 1.0f / (sm1 + 1e-8f);
        float2 r0, r1;
        r0.x = v0.x * inv0 * w0 + q0;
        r0.y = v0.y * inv0 * w0 + q0;
        r1.x = v1.x * inv1 * w1 + q1;
        r1.y = v1.y * inv1 * w1 + q1;
        resb[(size_t)t * F + f0] = r0;
        smb[(size_t)t * F + f0] = sm0;
        if (has2) {
            resb[(size_t)t * F + f1] = r1;
            smb[(size_t)t * F + f1] = sm1;
        }
    }
    if (c == NC - 1) {
        out[OFF_SFINAL + (size_t)b * F + f0] = s0;   // pre-sqrt state
        if (has2) out[OFF_SFINAL + (size_t)b * F + f1] = s1;
    }
}

extern "C" void kernel_launch(void* const* d_in, const int* in_sizes, int n_in,
                              void* d_out, int out_size, void* d_ws, size_t ws_size,
                              hipStream_t stream) {
    const float* input       = (const float*)d_in[0];
    const float* s_1         = (const float*)d_in[1];
    const float* weights     = (const float*)d_in[2];
    const float* bias        = (const float*)d_in[3];
    const float* alpha_param = (const float*)d_in[4];
    float* out = (float*)d_out;

    float* carry = (float*)d_ws;   // B*NC*F floats = 1.64 MB

    k_phase1<<<G1 + G0, 256, 0, stream>>>(input, alpha_param, weights, bias, carry, out);
    k_phase2<<<G0, 256, 0, stream>>>(input, s_1, alpha_param, weights, bias, carry, out);
}

// Round 4
// 297.990 us; speedup vs baseline: 1.0490x; 1.0490x over previous
//
#include <hip/hip_runtime.h>
#include <math.h>

#define B 16
#define C 2
#define T 2000
#define F 257
#define NC 100           // chunks per (b,f)
#define L  (T / NC)      // 20 timesteps per chunk

#define RES_SIZE   (B * C * T * F * 2)   // 32,896,000
#define OFF_SFINAL (RES_SIZE)            // + B*F
#define OFF_SMOOTH (RES_SIZE + B * F)    // + B*T*F

#define N_CARRY (B * NC * F)             // 411,200 threads (carries / phase-2)
#define G0      ((N_CARRY + 255) / 256)  // 1607 blocks
#define SLAB4   (T * F * 2 / 4)          // 257,000 float4 per (b, ch1) slab
#define N_V4    (B * SLAB4)              // 4,112,000 float4 threads for ch1
#define G1      ((N_V4 + 255) / 256)     // 16,063 blocks

__device__ __forceinline__ float sigmoidf_(float x) {
    return 1.0f / (1.0f + expf(-x));
}

// Phase 1 (fused): blocks [0,G1) do the channel-1 elementwise path (float4);
// blocks [G1, G1+G0) compute ch0 per-chunk carries (one f per thread — the
// round-3 f-pairing regressed ~13 µs and is reverted).
// Carries run LAST so the ch0 input is as fresh as possible in L3 when
// phase 2 re-reads it.
__global__ __launch_bounds__(256) void k_phase1(const float* __restrict__ input,
                                                const float* __restrict__ alpha_param,
                                                const float* __restrict__ weights,
                                                const float* __restrict__ bias,
                                                float* __restrict__ carry,
                                                float* __restrict__ out) {
    int bid = blockIdx.x;
    if (bid < G1) {
        // ---- channel 1: pure elementwise, float4-vectorized ----
        int idx = bid * 256 + threadIdx.x;
        if (idx >= N_V4) return;
        int b   = idx / SLAB4;
        int rem = idx - b * SLAB4;

        const float4* ip = (const float4*)(input + ((size_t)(b * C + 1) * T) * F * 2) + rem;
        float4 v = *ip;

        int e  = rem * 2;              // float2 index within slab
        int f0 = e % F;                // magic-mul, F=257 constant
        int f1 = (f0 + 1 == F) ? 0 : (f0 + 1);

        float w0 = weights[F + f0], w1 = weights[F + f1];
        float q0 = bias[F + f0],    q1 = bias[F + f1];

        float inv0 = 1.0f / (sqrtf(v.x * v.x + v.y * v.y) + 1e-8f);
        float inv1 = 1.0f / (sqrtf(v.z * v.z + v.w * v.w) + 1e-8f);

        float4 rr;
        rr.x = v.x * inv0 * w0 + q0;
        rr.y = v.y * inv0 * w0 + q0;
        rr.z = v.z * inv1 * w1 + q1;
        rr.w = v.w * inv1 * w1 + q1;

        float4* rp = (float4*)(out + ((size_t)(b * C + 1) * T) * F * 2) + rem;
        *rp = rr;
    } else {
        // ---- chunk carries: recurrence with s=0 over L steps ----
        int tid = (bid - G1) * 256 + threadIdx.x;
        if (tid >= N_CARRY) return;
        int f = tid % F;
        int r = tid / F;
        int c = r % NC;
        int b = r / NC;

        float a = sigmoidf_(alpha_param[f]);
        float beta = 1.0f - a;

        const float2* inp = (const float2*)input
                          + ((size_t)(b * C + 0) * T + (size_t)c * L) * F + f;
        float s = 0.0f;
#pragma unroll
        for (int t = 0; t < L; ++t) {
            float2 v = inp[(size_t)t * F];
            s = beta * s + a * (v.x * v.x + v.y * v.y);
        }
        carry[((size_t)b * NC + c) * F + f] = s;
    }
}

// Phase 2 (fused scan + final): each (b,c,f) thread folds its own chunk-start
// state from the L2-resident carry buffer, runs the exact per-step
// recurrence, writes res ch0 + smooth; c==NC-1 threads emit s_final.
__global__ __launch_bounds__(256) void k_phase2(const float* __restrict__ input,
                                                const float* __restrict__ s_1,
                                                const float* __restrict__ alpha_param,
                                                const float* __restrict__ weights,
                                                const float* __restrict__ bias,
                                                const float* __restrict__ carry,
                                                float* __restrict__ out) {
    int tid = blockIdx.x * 256 + threadIdx.x;
    if (tid >= N_CARRY) return;
    int f = tid % F;
    int r = tid / F;
    int c = r % NC;
    int b = r / NC;

    float a = sigmoidf_(alpha_param[f]);
    float beta = 1.0f - a;
    float bL = 1.0f;
#pragma unroll
    for (int i = 0; i < L; ++i) bL *= beta;
    float bL2 = bL * bL;
    float bL3 = bL2 * bL;
    float bL4 = bL2 * bL2;

    // redundant per-thread prefix over carries (L2-resident, 1.6 MB buffer);
    // 4-way unrolled: 4 independent loads per iteration, short dep chain
    const float* cp = carry + (size_t)b * NC * F + f;
    float s = s_1[b * F + f];
    int j = 0;
    for (; j + 4 <= c; j += 4) {
        float c0 = cp[(size_t)(j    ) * F];
        float c1 = cp[(size_t)(j + 1) * F];
        float c2 = cp[(size_t)(j + 2) * F];
        float c3 = cp[(size_t)(j + 3) * F];
        s = fmaf(bL4, s, fmaf(bL3, c0, fmaf(bL2, c1, fmaf(bL, c2, c3))));
    }
    for (; j < c; ++j) s = fmaf(bL, s, cp[(size_t)j * F]);

    float w0 = weights[f];   // channel 0
    float q0 = bias[f];

    const float2* inp = (const float2*)input
                      + ((size_t)(b * C + 0) * T + (size_t)c * L) * F + f;
    float2* res = (float2*)out
                + ((size_t)(b * C + 0) * T + (size_t)c * L) * F + f;
    float* smooth = out + OFF_SMOOTH + ((size_t)b * T + (size_t)c * L) * F + f;

#pragma unroll
    for (int t = 0; t < L; ++t) {
        float2 v = inp[(size_t)t * F];
        float x = v.x * v.x + v.y * v.y;
        s = beta * s + a * x;
        float sm = sqrtf(s);
        float inv = 1.0f / (sm + 1e-8f);
        float2 rr;
        rr.x = v.x * inv * w0 + q0;
        rr.y = v.y * inv * w0 + q0;
        res[(size_t)t * F] = rr;
        smooth[(size_t)t * F] = sm;
    }
    if (c == NC - 1) out[OFF_SFINAL + (size_t)b * F + f] = s;  // pre-sqrt state
}

extern "C" void kernel_launch(void* const* d_in, const int* in_sizes, int n_in,
                              void* d_out, int out_size, void* d_ws, size_t ws_size,
                              hipStream_t stream) {
    const float* input       = (const float*)d_in[0];
    const float* s_1         = (const float*)d_in[1];
    const float* weights     = (const float*)d_in[2];
    const float* bias        = (const float*)d_in[3];
    const float* alpha_param = (const float*)d_in[4];
    float* out = (float*)d_out;

    float* carry = (float*)d_ws;   // B*NC*F floats = 1.64 MB

    k_phase1<<<G1 + G0, 256, 0, stream>>>(input, alpha_param, weights, bias, carry, out);
    k_phase2<<<G0, 256, 0, stream>>>(input, s_1, alpha_param, weights, bias, carry, out);
}